// Round 8
// baseline (241.497 us; speedup 1.0000x reference)
//
#include <hip/hip_runtime.h>
#include <hip/hip_bf16.h>
#include <math.h>

// Problem constants
#define BB 256
#define DD 512
#define LL 196
#define NN 1024
#define MM 512
#define KK 10000

// ---- output layout (float offsets) ----
#define OUT_PY 0
#define OUT_HN ((size_t)2560000)
#define OUT_CN ((size_t)2822144)
#define OUT_AL ((size_t)3084288)

// ---- workspace layout (float offsets) ----
#define OFF_Z      ((size_t)0)        // B*512  = 131072
#define OFF_EMB    ((size_t)131072)   // B*512  = 131072
#define OFF_DEEP   ((size_t)262144)   // B*512  = 131072
#define OFF_EMBP   ((size_t)393216)   // 8  * B*512  = 1048576
#define OFF_GATESP ((size_t)1441792)  // 6  * B*4096 = 6291456
#define OFF_DP     ((size_t)7733248)  // 24 * B*512  = 3145728
// end 10878976 floats = 43.5 MB

typedef __attribute__((ext_vector_type(8))) short short8v;
typedef __attribute__((ext_vector_type(4))) float f32x4;

__device__ __forceinline__ unsigned short f2bf(float f) {
    unsigned int u = __builtin_bit_cast(unsigned int, f);
    u += 0x7fffu + ((u >> 16) & 1u);            // RNE
    return (unsigned short)(u >> 16);
}
__device__ __forceinline__ unsigned int pk2(float a, float b) {
    return ((unsigned int)f2bf(b) << 16) | (unsigned int)f2bf(a);
}
__device__ __forceinline__ float bflo(unsigned int u) {
    return __builtin_bit_cast(float, u << 16);
}
__device__ __forceinline__ float bfhi(unsigned int u) {
    return __builtin_bit_cast(float, u & 0xffff0000u);
}

// load 8 k-contiguous floats (guarded) -> bf16x8
__device__ __forceinline__ short8v stage8(const float* __restrict__ p, bool ok,
                                          int kbase, int Ktot) {
    short8v v;
    if (ok && (kbase + 7 < Ktot)) {
        const float4 x = *(const float4*)(p + kbase);
        const float4 y = *(const float4*)(p + kbase + 4);
        v[0] = (short)f2bf(x.x); v[1] = (short)f2bf(x.y);
        v[2] = (short)f2bf(x.z); v[3] = (short)f2bf(x.w);
        v[4] = (short)f2bf(y.x); v[5] = (short)f2bf(y.y);
        v[6] = (short)f2bf(y.z); v[7] = (short)f2bf(y.w);
    } else {
#pragma unroll
        for (int i = 0; i < 8; ++i) {
            const int k = kbase + i;
            v[i] = (short)f2bf((ok && k < Ktot) ? p[k] : 0.f);
        }
    }
    return v;
}

struct GSrc { const float* A; int lda; const float* B; int ldb; int ktn; int K; };

// Dual-source TN GEMM body (bf16 MFMA), 64x64 tile, BK=64, 256 threads.
__device__ __forceinline__ void gemm_body(
    const int bx, const int by, const int bz, const int rowBlocks,
    const GSrc s1, const GSrc s2,
    float* __restrict__ C, const int ldc, const int Ncols,
    const int ktPerSplit, const float* __restrict__ bias,
    short (*As)[64][72], short (*Bs)[64][72])
{
    const int t = threadIdx.x;
    const int row0 = bx * 64;
    const int col0 = by * 64;
    const int ktTot = s1.ktn + s2.ktn;
    const int kt0 = bz * ktPerSplit;
    const int nk = min(ktTot, kt0 + ktPerSplit) - kt0;

    const int sr = t >> 2;
    const int sk = (t & 3) << 4;
    const int bc = col0 + sr;
    const bool bok = (bc < Ncols);
    const float* aP1 = s1.A + (size_t)(row0 + sr) * s1.lda;
    const float* bP1 = s1.B + (size_t)(bok ? bc : 0) * s1.ldb;
    const float* aP2 = s2.A ? (s2.A + (size_t)(row0 + sr) * s2.lda) : aP1;
    const float* bP2 = s2.A ? (s2.B + (size_t)(bok ? bc : 0) * s2.ldb) : bP1;

    const int l = t & 63, w = t >> 6;
    const int wrow = (w >> 1) * 32, wcol = (w & 1) * 32;
    const int lr = l & 15, g = l >> 4, g8 = g * 8;

    f32x4 acc[2][2] = {};

    short8v sa0, sa1, sb0, sb1;
    {
        const int ktg = kt0;
        const float* aR; const float* bR; int kk, Kt;
        if (ktg < s1.ktn) { aR = aP1; bR = bP1; kk = (ktg << 6) + sk; Kt = s1.K; }
        else              { aR = aP2; bR = bP2; kk = ((ktg - s1.ktn) << 6) + sk; Kt = s2.K; }
        sa0 = stage8(aR, true, kk, Kt);  sa1 = stage8(aR, true, kk + 8, Kt);
        sb0 = stage8(bR, bok,  kk, Kt);  sb1 = stage8(bR, bok,  kk + 8, Kt);
    }
    *(short8v*)&As[0][sr][sk] = sa0; *(short8v*)&As[0][sr][sk + 8] = sa1;
    *(short8v*)&Bs[0][sr][sk] = sb0; *(short8v*)&Bs[0][sr][sk + 8] = sb1;
    __syncthreads();

    int cur = 0;
    for (int kt = 0; kt < nk; ++kt) {
        const bool more = (kt + 1 < nk);
        if (more) {
            const int ktg = kt0 + kt + 1;
            const float* aR; const float* bR; int kk, Kt;
            if (ktg < s1.ktn) { aR = aP1; bR = bP1; kk = (ktg << 6) + sk; Kt = s1.K; }
            else              { aR = aP2; bR = bP2; kk = ((ktg - s1.ktn) << 6) + sk; Kt = s2.K; }
            sa0 = stage8(aR, true, kk, Kt);  sa1 = stage8(aR, true, kk + 8, Kt);
            sb0 = stage8(bR, bok,  kk, Kt);  sb1 = stage8(bR, bok,  kk + 8, Kt);
        }
#pragma unroll
        for (int ks = 0; ks < 2; ++ks) {
            const int ko = ks * 32 + g8;
            short8v a0 = *(const short8v*)&As[cur][wrow + lr][ko];
            short8v a1 = *(const short8v*)&As[cur][wrow + 16 + lr][ko];
            short8v b0 = *(const short8v*)&Bs[cur][wcol + lr][ko];
            short8v b1 = *(const short8v*)&Bs[cur][wcol + 16 + lr][ko];
            acc[0][0] = __builtin_amdgcn_mfma_f32_16x16x32_bf16(a0, b0, acc[0][0], 0, 0, 0);
            acc[0][1] = __builtin_amdgcn_mfma_f32_16x16x32_bf16(a0, b1, acc[0][1], 0, 0, 0);
            acc[1][0] = __builtin_amdgcn_mfma_f32_16x16x32_bf16(a1, b0, acc[1][0], 0, 0, 0);
            acc[1][1] = __builtin_amdgcn_mfma_f32_16x16x32_bf16(a1, b1, acc[1][1], 0, 0, 0);
        }
        if (more) {
            *(short8v*)&As[cur ^ 1][sr][sk] = sa0;
            *(short8v*)&As[cur ^ 1][sr][sk + 8] = sa1;
            *(short8v*)&Bs[cur ^ 1][sr][sk] = sb0;
            *(short8v*)&Bs[cur ^ 1][sr][sk + 8] = sb1;
        }
        __syncthreads();
        cur ^= 1;
    }

    float* Cp = C + (size_t)bz * ((size_t)rowBlocks * 64) * ldc;
#pragma unroll
    for (int m = 0; m < 2; ++m)
#pragma unroll
        for (int n = 0; n < 2; ++n)
#pragma unroll
            for (int j = 0; j < 4; ++j) {
                const int r = row0 + wrow + m * 16 + g * 4 + j;
                const int c = col0 + wcol + n * 16 + lr;
                if (c < Ncols) {
                    float v = acc[m][n][j];
                    if (bias) v += bias[c];
                    Cp[(size_t)r * ldc + c] = v;
                }
            }
}

// ==== K1: single-pass attention (256 blocks) || emb GEMM (256) || gates_h GEMM (1024)
// att: block b; thread t holds rows d=t and d=t+256 of a_i[b] as bf16 in regs.
// a_i read from HBM exactly once.
__global__ __launch_bounds__(256, 2) void k1_att_emb_gatesh(
    const float* __restrict__ a_i, const float* __restrict__ h,
    const float* __restrict__ f_att_w, const float* __restrict__ f_att_b,
    const float* __restrict__ gate_w, const float* __restrict__ gate_b,
    float* __restrict__ alpha_out, float* __restrict__ z,
    const float* __restrict__ inp, const float* __restrict__ E_w,
    float* __restrict__ embp,
    const float* __restrict__ W_ih, const float* __restrict__ W_hh,
    float* __restrict__ gatesp)
{
    __shared__ __align__(16) unsigned char smem[36864];
    const int bid = blockIdx.x;
    const int t = threadIdx.x;

    if (bid < 256) {
        // ---- attention role ----
        unsigned int* chunk = (unsigned int*)smem;           // [64][102] u32 (bf16x2)
        float* wsh = (float*)(smem + 26112);                 // [512] w_a
        float* al  = wsh + 512;                              // [200] alpha
        float* red = al + 200;                               // [32]
        float* sc2 = red + 32;                               // [2]
        const int lane = t & 63, w = t >> 6;
        const int b = bid;

        wsh[t] = f_att_w[t];
        wsh[t + 256] = f_att_w[t + 256];

        // h dots
        const float4 h4 = *(const float4*)(h + (size_t)b * NN + t * 4);
        const float4 w4 = *(const float4*)(f_att_w + DD + t * 4);
        const float4 g4 = *(const float4*)(gate_w + t * 4);
        float hd = h4.x * w4.x + h4.y * w4.y + h4.z * w4.z + h4.w * w4.w;
        float gd = h4.x * g4.x + h4.y * g4.y + h4.z * g4.z + h4.w * g4.w;
#pragma unroll
        for (int off = 32; off > 0; off >>= 1) {
            hd += __shfl_down(hd, off, 64);
            gd += __shfl_down(gd, off, 64);
        }
        if (lane == 0) { red[w] = hd; red[16 + w] = gd; }

        // stream both rows (contiguous 784B each) into regs as bf16
        unsigned int r0[98], r1[98];
        const float* p0 = a_i + ((size_t)b * DD + t) * LL;
        const float* p1 = p0 + (size_t)256 * LL;
#pragma unroll
        for (int j = 0; j < 49; ++j) {
            const float4 v = *(const float4*)(p0 + j * 4);
            r0[2 * j]     = pk2(v.x, v.y);
            r0[2 * j + 1] = pk2(v.z, v.w);
        }
#pragma unroll
        for (int j = 0; j < 49; ++j) {
            const float4 v = *(const float4*)(p1 + j * 4);
            r1[2 * j]     = pk2(v.x, v.y);
            r1[2 * j + 1] = pk2(v.z, v.w);
        }
        __syncthreads();
        if (t == 0) {
            sc2[0] = red[0] + red[1] + red[2] + red[3];
            sc2[1] = red[16] + red[17] + red[18] + red[19];
        }

        // e-reduction: 8 chunks of 64 rows staged through LDS (deterministic)
        float e_acc = 0.f;
#pragma unroll
        for (int c = 0; c < 8; ++c) {
            __syncthreads();                       // chunk buffer free
            if (w == (c & 3)) {
                unsigned int* dst = chunk + lane * 102;
                if (c < 4) {
#pragma unroll
                    for (int j = 0; j < 49; ++j) {
                        uint2 uv; uv.x = r0[2 * j]; uv.y = r0[2 * j + 1];
                        *(uint2*)(dst + 2 * j) = uv;
                    }
                } else {
#pragma unroll
                    for (int j = 0; j < 49; ++j) {
                        uint2 uv; uv.x = r1[2 * j]; uv.y = r1[2 * j + 1];
                        *(uint2*)(dst + 2 * j) = uv;
                    }
                }
            }
            __syncthreads();
            if (t < LL) {
                const float* wc = wsh + c * 64;
                const unsigned short* cs = (const unsigned short*)chunk;
#pragma unroll
                for (int d = 0; d < 64; ++d) {
                    const float av = __builtin_bit_cast(
                        float, (unsigned int)cs[d * 204 + t] << 16);
                    e_acc += av * wc[d];
                }
            }
        }
        __syncthreads();

        // softmax over l
        float e = (t < LL) ? (e_acc + sc2[0] + f_att_b[0]) : -3.4e38f;
        float m = e;
#pragma unroll
        for (int off = 32; off > 0; off >>= 1) m = fmaxf(m, __shfl_down(m, off, 64));
        if (lane == 0) red[w] = m;
        __syncthreads();
        const float mx = fmaxf(fmaxf(red[0], red[1]), fmaxf(red[2], red[3]));
        const float ex = (t < LL) ? expf(e - mx) : 0.f;
        float s = ex;
#pragma unroll
        for (int off = 32; off > 0; off >>= 1) s += __shfl_down(s, off, 64);
        if (lane == 0) red[16 + w] = s;
        __syncthreads();
        const float inv = 1.f / (red[16] + red[17] + red[18] + red[19]);
        if (t < LL) {
            const float a = ex * inv;
            al[t] = a;
            alpha_out[(size_t)b * LL + t] = a;
        }
        __syncthreads();

        // z from register rows
        float d0 = 0.f, d1 = 0.f;
#pragma unroll
        for (int j = 0; j < 49; ++j) {
            const float4 a4 = *(const float4*)(al + 4 * j);
            d0 += bflo(r0[2 * j]) * a4.x + bfhi(r0[2 * j]) * a4.y
                + bflo(r0[2 * j + 1]) * a4.z + bfhi(r0[2 * j + 1]) * a4.w;
            d1 += bflo(r1[2 * j]) * a4.x + bfhi(r1[2 * j]) * a4.y
                + bflo(r1[2 * j + 1]) * a4.z + bfhi(r1[2 * j + 1]) * a4.w;
        }
        const float beta = 1.f / (1.f + expf(-(sc2[1] + gate_b[0])));
        z[(size_t)b * DD + t] = beta * d0;
        z[(size_t)b * DD + 256 + t] = beta * d1;
    } else if (bid < 512) {
        // ---- emb GEMM: inp @ E_w^T, 8 split-K slices ----
        short (*As)[64][72] = (short (*)[64][72])smem;
        short (*Bs)[64][72] = (short (*)[64][72])(smem + 18432);
        const int i = bid - 256;                   // 256 = 4*8*8
        GSrc s1 = {inp, KK, E_w, KK, 157, KK};
        GSrc s2 = {nullptr, 0, nullptr, 0, 0, 0};
        gemm_body(i & 3, (i >> 2) & 7, i >> 5, 4, s1, s2,
                  embp, MM, MM, 20, nullptr, As, Bs);
    } else {
        // ---- gates_h GEMM: h@W_ih[:,512:1536]^T + h@W_hh^T, slices 0..3 ----
        short (*As)[64][72] = (short (*)[64][72])smem;
        short (*Bs)[64][72] = (short (*)[64][72])(smem + 18432);
        const int i = bid - 512;                   // 1024 = 4*64*4
        GSrc s1 = {h, NN, W_ih + 512, 2048, 16, NN};
        GSrc s2 = {h, NN, W_hh, NN, 16, NN};
        gemm_body(i & 3, (i >> 2) & 63, i >> 8, 4, s1, s2,
                  gatesp, 4096, 4096, 8, nullptr, As, Bs);
    }
}

// ==== K2: emb partial reduce ====
__global__ __launch_bounds__(256) void k2_embred(
    const float* __restrict__ embp, const float* __restrict__ E_b,
    float* __restrict__ emb)
{
    const int idx = blockIdx.x * 256 + threadIdx.x;   // < B*512
    const int j = idx & 511;
    float v = E_b[j];
#pragma unroll
    for (int s = 0; s < 8; ++s) v += embp[(size_t)s * (BB * 512) + idx];
    emb[idx] = v;
}

// ==== K3: gates_ez GEMM (512) || lz GEMM (256) ====
__global__ __launch_bounds__(256) void k3_gatesez_lz(
    const float* __restrict__ emb, const float* __restrict__ z,
    const float* __restrict__ W_ih, float* __restrict__ gatesp_hi,
    const float* __restrict__ Lz_w, float* __restrict__ dp)
{
    __shared__ __align__(16) unsigned char smem[36864];
    short (*As)[64][72] = (short (*)[64][72])smem;
    short (*Bs)[64][72] = (short (*)[64][72])(smem + 18432);
    const int bid = blockIdx.x;
    if (bid < 512) {                                  // 4*64*2
        GSrc s1 = {emb, MM, W_ih, 2048, 8, MM};
        GSrc s2 = {z, DD, W_ih + 1536, 2048, 8, DD};
        gemm_body(bid & 3, (bid >> 2) & 63, bid >> 8, 4, s1, s2,
                  gatesp_hi, 4096, 4096, 8, nullptr, As, Bs);
    } else {
        const int i = bid - 512;                      // 256 = 4*8*8
        GSrc s1 = {z, DD, Lz_w, DD, 8, DD};
        GSrc s2 = {nullptr, 0, nullptr, 0, 0, 0};
        gemm_body(i & 3, (i >> 2) & 7, i >> 5, 4, s1, s2,
                  dp, MM, MM, 1, nullptr, As, Bs);
    }
}

// ==== K4: LSTM cell ====
__global__ __launch_bounds__(256) void k4_lstm(
    const float* __restrict__ gatesp,
    const float* __restrict__ b_ih, const float* __restrict__ b_hh,
    const float* __restrict__ c_prev, float* __restrict__ hn, float* __restrict__ cn)
{
    const int idx = blockIdx.x * 256 + threadIdx.x;   // < B*1024
    const int b = idx >> 10, n = idx & 1023;
    float g[4];
#pragma unroll
    for (int gi = 0; gi < 4; ++gi) {
        const int col = gi * 1024 + n;
        const size_t o = (size_t)b * 4096 + col;
        float v = b_ih[col] + b_hh[col];
#pragma unroll
        for (int s = 0; s < 6; ++s) v += gatesp[(size_t)s * (BB * 4096) + o];
        g[gi] = v;
    }
    const float si = 1.f / (1.f + expf(-g[0]));
    const float sf = 1.f / (1.f + expf(-g[1]));
    const float so = 1.f / (1.f + expf(-g[3]));
    const float tg = tanhf(g[2]);
    const float c = c_prev[idx];
    const float cnv = sf * c + si * tg;
    const float hnv = so * tanhf(cnv);
    cn[idx] = cnv;
    hn[idx] = hnv;
}

// ==== K5: lh GEMM (512 blocks) ====
__global__ __launch_bounds__(256) void k5_lh(
    const float* __restrict__ hn, const float* __restrict__ Lh_w,
    float* __restrict__ dp_hi)
{
    __shared__ __align__(16) unsigned char smem[36864];
    short (*As)[64][72] = (short (*)[64][72])smem;
    short (*Bs)[64][72] = (short (*)[64][72])(smem + 18432);
    const int bid = blockIdx.x;                       // 512 = 4*8*16
    GSrc s1 = {hn, NN, Lh_w, NN, 16, NN};
    GSrc s2 = {nullptr, 0, nullptr, 0, 0, 0};
    gemm_body(bid & 3, (bid >> 2) & 7, bid >> 5, 4, s1, s2,
              dp_hi, MM, MM, 1, nullptr, As, Bs);
}

// ==== K6: build deep ====
__global__ __launch_bounds__(256) void k6_deep(
    const float* __restrict__ emb, const float* __restrict__ dp,
    const float* __restrict__ Lh_b, const float* __restrict__ Lz_b,
    float* __restrict__ deep)
{
    const int idx = blockIdx.x * 256 + threadIdx.x;   // < B*512
    const int j = idx & 511;
    float v = emb[idx] + Lh_b[j] + Lz_b[j];
#pragma unroll
    for (int s = 0; s < 24; ++s) v += dp[(size_t)s * (BB * 512) + idx];
    deep[idx] = v;
}

// ==== K7: p_yt GEMM (628 blocks) ====
__global__ __launch_bounds__(256) void k7_pyt(
    const float* __restrict__ deep, const float* __restrict__ Lo_w,
    const float* __restrict__ Lo_b, float* __restrict__ out)
{
    __shared__ __align__(16) unsigned char smem[36864];
    short (*As)[64][72] = (short (*)[64][72])smem;
    short (*Bs)[64][72] = (short (*)[64][72])(smem + 18432);
    const int bid = blockIdx.x;                       // 628 = 4*157
    GSrc s1 = {deep, MM, Lo_w, MM, 8, MM};
    GSrc s2 = {nullptr, 0, nullptr, 0, 0, 0};
    gemm_body(bid & 3, bid >> 2, 0, 4, s1, s2,
              out, KK, KK, 8, Lo_b, As, Bs);
}

extern "C" void kernel_launch(void* const* d_in, const int* in_sizes, int n_in,
                              void* d_out, int out_size, void* d_ws, size_t ws_size,
                              hipStream_t stream)
{
    const float* a_i     = (const float*)d_in[0];
    const float* inp     = (const float*)d_in[1];
    const float* hn_prev = (const float*)d_in[2];
    const float* cn_prev = (const float*)d_in[3];
    const float* f_att_w = (const float*)d_in[4];
    const float* f_att_b = (const float*)d_in[5];
    const float* gate_w  = (const float*)d_in[6];
    const float* gate_b  = (const float*)d_in[7];
    const float* E_w     = (const float*)d_in[8];
    const float* E_b     = (const float*)d_in[9];
    const float* W_ih    = (const float*)d_in[10];
    const float* W_hh    = (const float*)d_in[11];
    const float* b_ih    = (const float*)d_in[12];
    const float* b_hh    = (const float*)d_in[13];
    const float* Lh_w    = (const float*)d_in[14];
    const float* Lh_b    = (const float*)d_in[15];
    const float* Lz_w    = (const float*)d_in[16];
    const float* Lz_b    = (const float*)d_in[17];
    const float* Lo_w    = (const float*)d_in[18];
    const float* Lo_b    = (const float*)d_in[19];

    float* out = (float*)d_out;
    float* ws  = (float*)d_ws;

    float* Z      = ws + OFF_Z;
    float* EMB    = ws + OFF_EMB;
    float* DEEP   = ws + OFF_DEEP;
    float* EMBP   = ws + OFF_EMBP;
    float* GATESP = ws + OFF_GATESP;
    float* DP     = ws + OFF_DP;

    // K1: single-pass attention || emb GEMM || gates_h GEMM
    k1_att_emb_gatesh<<<1536, 256, 0, stream>>>(
        a_i, hn_prev, f_att_w, f_att_b, gate_w, gate_b,
        out + OUT_AL, Z, inp, E_w, EMBP, W_ih, W_hh, GATESP);

    // K2: emb = sum(embp) + E_b
    k2_embred<<<512, 256, 0, stream>>>(EMBP, E_b, EMB);

    // K3: gates emb/z parts (slices 4..5) || z@Lz_w^T (dp slices 0..7)
    k3_gatesez_lz<<<768, 256, 0, stream>>>(EMB, Z, W_ih,
                                           GATESP + (size_t)4 * BB * 4096,
                                           Lz_w, DP);

    // K4: LSTM cell
    k4_lstm<<<1024, 256, 0, stream>>>(GATESP, b_ih, b_hh, cn_prev,
                                      out + OUT_HN, out + OUT_CN);

    // K5: hn@Lh_w^T (dp slices 8..23)
    k5_lh<<<512, 256, 0, stream>>>(out + OUT_HN, Lh_w,
                                   DP + (size_t)8 * BB * 512);

    // K6: deep = emb + sum(dp) + biases
    k6_deep<<<512, 256, 0, stream>>>(EMB, DP, Lh_b, Lz_b, DEEP);

    // K7: p_yt = deep @ Lo_w^T + Lo_b
    k7_pyt<<<628, 256, 0, stream>>>(DEEP, Lo_w, Lo_b, out + OUT_PY);
}

// Round 9
// 156.298 us; speedup vs baseline: 1.5451x; 1.5451x over previous
//
#include <hip/hip_runtime.h>
#include <hip/hip_bf16.h>
#include <math.h>

// Problem constants
#define BB 256
#define DD 512
#define LL 196
#define NN 1024
#define MM 512
#define KK 10000

// ---- output layout (float offsets) ----
#define OUT_PY 0
#define OUT_HN ((size_t)2560000)
#define OUT_CN ((size_t)2822144)
#define OUT_AL ((size_t)3084288)

// ---- workspace layout (float offsets) ----
#define OFF_PE     ((size_t)0)         // B*16*196 = 802816
#define OFF_BETA   ((size_t)802816)    // 256
#define OFF_Z      ((size_t)803072)    // B*512  = 131072
#define OFF_EMB    ((size_t)934144)    // B*512  = 131072
#define OFF_DEEP   ((size_t)1065216)   // B*512  = 131072
#define OFF_EMBP   ((size_t)1196288)   // 8  * B*512  = 1048576
#define OFF_GATESP ((size_t)2244864)   // 8  * B*4096 = 8388608
#define OFF_DP     ((size_t)10633472)  // 24 * B*512  = 3145728
// end 13779200 floats = 55.1 MB

typedef __attribute__((ext_vector_type(8))) short short8v;
typedef __attribute__((ext_vector_type(4))) float f32x4;

__device__ __forceinline__ unsigned short f2bf(float f) {
    unsigned int u = __builtin_bit_cast(unsigned int, f);
    u += 0x7fffu + ((u >> 16) & 1u);            // RNE
    return (unsigned short)(u >> 16);
}

// load 8 k-contiguous floats (guarded) -> bf16x8
__device__ __forceinline__ short8v stage8(const float* __restrict__ p, bool ok,
                                          int kbase, int Ktot) {
    short8v v;
    if (ok && (kbase + 7 < Ktot)) {
        const float4 x = *(const float4*)(p + kbase);
        const float4 y = *(const float4*)(p + kbase + 4);
        v[0] = (short)f2bf(x.x); v[1] = (short)f2bf(x.y);
        v[2] = (short)f2bf(x.z); v[3] = (short)f2bf(x.w);
        v[4] = (short)f2bf(y.x); v[5] = (short)f2bf(y.y);
        v[6] = (short)f2bf(y.z); v[7] = (short)f2bf(y.w);
    } else {
#pragma unroll
        for (int i = 0; i < 8; ++i) {
            const int k = kbase + i;
            v[i] = (short)f2bf((ok && k < Ktot) ? p[k] : 0.f);
        }
    }
    return v;
}

struct GSrc { const float* A; int lda; const float* B; int ldb; int ktn; int K; };

// Dual-source TN GEMM body (bf16 MFMA), 64x64 tile, BK=64, 256 threads.
__device__ __forceinline__ void gemm_body(
    const int bx, const int by, const int bz, const int rowBlocks,
    const GSrc s1, const GSrc s2,
    float* __restrict__ C, const int ldc, const int Ncols,
    const int ktPerSplit, const float* __restrict__ bias,
    short (*As)[64][72], short (*Bs)[64][72])
{
    const int t = threadIdx.x;
    const int row0 = bx * 64;
    const int col0 = by * 64;
    const int ktTot = s1.ktn + s2.ktn;
    const int kt0 = bz * ktPerSplit;
    const int nk = min(ktTot, kt0 + ktPerSplit) - kt0;

    const int sr = t >> 2;
    const int sk = (t & 3) << 4;
    const int bc = col0 + sr;
    const bool bok = (bc < Ncols);
    const float* aP1 = s1.A + (size_t)(row0 + sr) * s1.lda;
    const float* bP1 = s1.B + (size_t)(bok ? bc : 0) * s1.ldb;
    const float* aP2 = s2.A ? (s2.A + (size_t)(row0 + sr) * s2.lda) : aP1;
    const float* bP2 = s2.A ? (s2.B + (size_t)(bok ? bc : 0) * s2.ldb) : bP1;

    const int l = t & 63, w = t >> 6;
    const int wrow = (w >> 1) * 32, wcol = (w & 1) * 32;
    const int lr = l & 15, g = l >> 4, g8 = g * 8;

    f32x4 acc[2][2] = {};

    short8v sa0, sa1, sb0, sb1;
    {
        const int ktg = kt0;
        const float* aR; const float* bR; int kk, Kt;
        if (ktg < s1.ktn) { aR = aP1; bR = bP1; kk = (ktg << 6) + sk; Kt = s1.K; }
        else              { aR = aP2; bR = bP2; kk = ((ktg - s1.ktn) << 6) + sk; Kt = s2.K; }
        sa0 = stage8(aR, true, kk, Kt);  sa1 = stage8(aR, true, kk + 8, Kt);
        sb0 = stage8(bR, bok,  kk, Kt);  sb1 = stage8(bR, bok,  kk + 8, Kt);
    }
    *(short8v*)&As[0][sr][sk] = sa0; *(short8v*)&As[0][sr][sk + 8] = sa1;
    *(short8v*)&Bs[0][sr][sk] = sb0; *(short8v*)&Bs[0][sr][sk + 8] = sb1;
    __syncthreads();

    int cur = 0;
    for (int kt = 0; kt < nk; ++kt) {
        const bool more = (kt + 1 < nk);
        if (more) {
            const int ktg = kt0 + kt + 1;
            const float* aR; const float* bR; int kk, Kt;
            if (ktg < s1.ktn) { aR = aP1; bR = bP1; kk = (ktg << 6) + sk; Kt = s1.K; }
            else              { aR = aP2; bR = bP2; kk = ((ktg - s1.ktn) << 6) + sk; Kt = s2.K; }
            sa0 = stage8(aR, true, kk, Kt);  sa1 = stage8(aR, true, kk + 8, Kt);
            sb0 = stage8(bR, bok,  kk, Kt);  sb1 = stage8(bR, bok,  kk + 8, Kt);
        }
#pragma unroll
        for (int ks = 0; ks < 2; ++ks) {
            const int ko = ks * 32 + g8;
            short8v a0 = *(const short8v*)&As[cur][wrow + lr][ko];
            short8v a1 = *(const short8v*)&As[cur][wrow + 16 + lr][ko];
            short8v b0 = *(const short8v*)&Bs[cur][wcol + lr][ko];
            short8v b1 = *(const short8v*)&Bs[cur][wcol + 16 + lr][ko];
            acc[0][0] = __builtin_amdgcn_mfma_f32_16x16x32_bf16(a0, b0, acc[0][0], 0, 0, 0);
            acc[0][1] = __builtin_amdgcn_mfma_f32_16x16x32_bf16(a0, b1, acc[0][1], 0, 0, 0);
            acc[1][0] = __builtin_amdgcn_mfma_f32_16x16x32_bf16(a1, b0, acc[1][0], 0, 0, 0);
            acc[1][1] = __builtin_amdgcn_mfma_f32_16x16x32_bf16(a1, b1, acc[1][1], 0, 0, 0);
        }
        if (more) {
            *(short8v*)&As[cur ^ 1][sr][sk] = sa0;
            *(short8v*)&As[cur ^ 1][sr][sk + 8] = sa1;
            *(short8v*)&Bs[cur ^ 1][sr][sk] = sb0;
            *(short8v*)&Bs[cur ^ 1][sr][sk + 8] = sb1;
        }
        __syncthreads();
        cur ^= 1;
    }

    float* Cp = C + (size_t)bz * ((size_t)rowBlocks * 64) * ldc;
#pragma unroll
    for (int m = 0; m < 2; ++m)
#pragma unroll
        for (int n = 0; n < 2; ++n)
#pragma unroll
            for (int j = 0; j < 4; ++j) {
                const int r = row0 + wrow + m * 16 + g * 4 + j;
                const int c = col0 + wcol + n * 16 + lr;
                if (c < Ncols) {
                    float v = acc[m][n][j];
                    if (bias) v += bias[c];
                    Cp[(size_t)r * ldc + c] = v;
                }
            }
}

// ==== K1: att_e (4096) || emb GEMM (256) || gates_h GEMM (1024) ====
// att_e: block (b, ch); wave w streams 8 rows of a_i[b, ch*32+w*8 ..] as
// float4 (lanes 0..48, 784 B/row), fully unrolled -> 6.3 KB in flight/wave.
__global__ __launch_bounds__(256) void k1_atte_emb_gatesh(
    const float* __restrict__ a_i, const float* __restrict__ f_att_w,
    float* __restrict__ pe,
    const float* __restrict__ inp, const float* __restrict__ E_w,
    float* __restrict__ embp,
    const float* __restrict__ h, const float* __restrict__ W_ih,
    const float* __restrict__ W_hh, float* __restrict__ gatesp)
{
    __shared__ __align__(16) unsigned char smem[36864];
    const int bid = blockIdx.x;
    const int t = threadIdx.x;

    if (bid < 4096) {
        float* pw = (float*)smem;                     // [4][200]
        const int b = bid >> 4, ch = bid & 15;
        const int w = t >> 6, lane = t & 63;
        const int d0 = ch * 32 + w * 8;
        const float* base = a_i + ((size_t)b * DD + d0) * LL;
        float e4[4] = {0.f, 0.f, 0.f, 0.f};
        if (lane < 49) {
            float4 rbuf[8];
#pragma unroll
            for (int i = 0; i < 8; ++i)
                rbuf[i] = *(const float4*)(base + (size_t)i * LL + lane * 4);
#pragma unroll
            for (int i = 0; i < 8; ++i) {
                const float wa = f_att_w[d0 + i];
                e4[0] += rbuf[i].x * wa; e4[1] += rbuf[i].y * wa;
                e4[2] += rbuf[i].z * wa; e4[3] += rbuf[i].w * wa;
            }
            *(float4*)&pw[w * 200 + lane * 4] = *(const float4*)e4;
        }
        __syncthreads();
        if (t < LL) {
            const float s = pw[t] + pw[200 + t] + pw[400 + t] + pw[600 + t];
            pe[((size_t)b * 16 + ch) * LL + t] = s;
        }
    } else if (bid < 4352) {
        short (*As)[64][72] = (short (*)[64][72])smem;
        short (*Bs)[64][72] = (short (*)[64][72])(smem + 18432);
        const int i = bid - 4096;                     // 256 = 4*8*8
        GSrc s1 = {inp, KK, E_w, KK, 157, KK};
        GSrc s2 = {nullptr, 0, nullptr, 0, 0, 0};
        gemm_body(i & 3, (i >> 2) & 7, i >> 5, 4, s1, s2,
                  embp, MM, MM, 20, nullptr, As, Bs);
    } else {
        short (*As)[64][72] = (short (*)[64][72])smem;
        short (*Bs)[64][72] = (short (*)[64][72])(smem + 18432);
        const int i = bid - 4352;                     // 1024 = 4*64*4
        GSrc s1 = {h, NN, W_ih + 512, 2048, 16, NN};
        GSrc s2 = {h, NN, W_hh, NN, 16, NN};
        gemm_body(i & 3, (i >> 2) & 63, i >> 8, 4, s1, s2,
                  gatesp, 4096, 4096, 8, nullptr, As, Bs);
    }
}

// ==== K2: softmax+beta (256) || emb partial reduce (512) ====
__global__ __launch_bounds__(256) void k2_softmax_embred(
    const float* __restrict__ pe, const float* __restrict__ h,
    const float* __restrict__ f_att_w, const float* __restrict__ f_att_b,
    const float* __restrict__ gate_w, const float* __restrict__ gate_b,
    float* __restrict__ alpha_out, float* __restrict__ beta,
    const float* __restrict__ embp, const float* __restrict__ E_b,
    float* __restrict__ emb)
{
    const int bid = blockIdx.x;
    const int t = threadIdx.x;
    if (bid < 256) {
        const int b = bid;
        __shared__ float red[256];
        __shared__ float red2[256];
        const float4 h4 = *(const float4*)(h + (size_t)b * NN + t * 4);
        const float4 w4 = *(const float4*)(f_att_w + DD + t * 4);
        const float4 g4 = *(const float4*)(gate_w + t * 4);
        float hd = h4.x * w4.x + h4.y * w4.y + h4.z * w4.z + h4.w * w4.w;
        float gd = h4.x * g4.x + h4.y * g4.y + h4.z * g4.z + h4.w * g4.w;
        red[t] = hd; red2[t] = gd;
        __syncthreads();
        for (int s = 128; s > 0; s >>= 1) {
            if (t < s) { red[t] += red[t + s]; red2[t] += red2[t + s]; }
            __syncthreads();
        }
        const float hdot = red[0];
        const float gdot = red2[0];
        __syncthreads();
        float e = -3.4e38f;
        if (t < LL) {
            const float* p = pe + (size_t)b * 16 * LL + t;
            e = hdot + f_att_b[0];
#pragma unroll
            for (int ch = 0; ch < 16; ++ch) e += p[ch * LL];
        }
        red[t] = e;
        __syncthreads();
        for (int s = 128; s > 0; s >>= 1) {
            if (t < s) red[t] = fmaxf(red[t], red[t + s]);
            __syncthreads();
        }
        const float mx = red[0];
        __syncthreads();
        const float ex = (t < LL) ? expf(e - mx) : 0.f;
        red[t] = ex;
        __syncthreads();
        for (int s = 128; s > 0; s >>= 1) {
            if (t < s) red[t] += red[t + s];
            __syncthreads();
        }
        const float inv = 1.f / red[0];
        if (t < LL) alpha_out[(size_t)b * LL + t] = ex * inv;
        if (t == 0) beta[b] = 1.f / (1.f + expf(-(gdot + gate_b[0])));
    } else {
        const int idx = (bid - 256) * 256 + t;        // < B*512
        const int j = idx & 511;
        float v = E_b[j];
#pragma unroll
        for (int s = 0; s < 8; ++s) v += embp[(size_t)s * (BB * 512) + idx];
        emb[idx] = v;
    }
}

// ==== K3: att_z (4096) || gates_e GEMM (512) ====
// att_z: same streaming pattern as att_e; a_i now L3-resident.
__global__ __launch_bounds__(256) void k3_attz_gatese(
    const float* __restrict__ a_i, const float* __restrict__ alpha,
    const float* __restrict__ beta, float* __restrict__ z,
    const float* __restrict__ emb, const float* __restrict__ W_ih,
    float* __restrict__ gatesp_e)
{
    __shared__ __align__(16) unsigned char smem[36864];
    const int bid = blockIdx.x;
    const int t = threadIdx.x;

    if (bid < 4096) {
        float* al = (float*)smem;                     // [200]
        const int b = bid >> 4, ch = bid & 15;
        const int w = t >> 6, lane = t & 63;
        if (t < LL) al[t] = alpha[(size_t)b * LL + t];
        __syncthreads();
        const int d0 = ch * 32 + w * 8;
        const float* base = a_i + ((size_t)b * DD + d0) * LL;
        const float bet = beta[b];
        float4 av = make_float4(0.f, 0.f, 0.f, 0.f);
        float4 rbuf[8];
        if (lane < 49) {
            av = *(const float4*)&al[lane * 4];
#pragma unroll
            for (int i = 0; i < 8; ++i)
                rbuf[i] = *(const float4*)(base + (size_t)i * LL + lane * 4);
        }
#pragma unroll
        for (int i = 0; i < 8; ++i) {
            float s = (lane < 49) ? (rbuf[i].x * av.x + rbuf[i].y * av.y +
                                     rbuf[i].z * av.z + rbuf[i].w * av.w) : 0.f;
#pragma unroll
            for (int off = 32; off > 0; off >>= 1) s += __shfl_down(s, off, 64);
            if (lane == 0) z[(size_t)b * DD + d0 + i] = bet * s;
        }
    } else {
        short (*As)[64][72] = (short (*)[64][72])smem;
        short (*Bs)[64][72] = (short (*)[64][72])(smem + 18432);
        const int i = bid - 4096;                     // 512 = 4*64*2
        GSrc s1 = {emb, MM, W_ih, 2048, 8, MM};
        GSrc s2 = {nullptr, 0, nullptr, 0, 0, 0};
        gemm_body(i & 3, (i >> 2) & 63, i >> 8, 4, s1, s2,
                  gatesp_e, 4096, 4096, 4, nullptr, As, Bs);
    }
}

// ==== K4: gates_z GEMM (512) || lz GEMM (256) ====
__global__ __launch_bounds__(256) void k4_gatesz_lz(
    const float* __restrict__ z, const float* __restrict__ W_ih,
    float* __restrict__ gatesp_z,
    const float* __restrict__ Lz_w, float* __restrict__ dp)
{
    __shared__ __align__(16) unsigned char smem[36864];
    short (*As)[64][72] = (short (*)[64][72])smem;
    short (*Bs)[64][72] = (short (*)[64][72])(smem + 18432);
    const int bid = blockIdx.x;
    if (bid < 512) {                                  // 4*64*2
        GSrc s1 = {z, DD, W_ih + 1536, 2048, 8, DD};
        GSrc s2 = {nullptr, 0, nullptr, 0, 0, 0};
        gemm_body(bid & 3, (bid >> 2) & 63, bid >> 8, 4, s1, s2,
                  gatesp_z, 4096, 4096, 4, nullptr, As, Bs);
    } else {
        const int i = bid - 512;                      // 256 = 4*8*8
        GSrc s1 = {z, DD, Lz_w, DD, 8, DD};
        GSrc s2 = {nullptr, 0, nullptr, 0, 0, 0};
        gemm_body(i & 3, (i >> 2) & 7, i >> 5, 4, s1, s2,
                  dp, MM, MM, 1, nullptr, As, Bs);
    }
}

// ==== K5: LSTM cell (sums 8 gate slices) ====
__global__ __launch_bounds__(256) void k5_lstm(
    const float* __restrict__ gatesp,
    const float* __restrict__ b_ih, const float* __restrict__ b_hh,
    const float* __restrict__ c_prev, float* __restrict__ hn, float* __restrict__ cn)
{
    const int idx = blockIdx.x * 256 + threadIdx.x;   // < B*1024
    const int b = idx >> 10, n = idx & 1023;
    float g[4];
#pragma unroll
    for (int gi = 0; gi < 4; ++gi) {
        const int col = gi * 1024 + n;
        const size_t o = (size_t)b * 4096 + col;
        float v = b_ih[col] + b_hh[col];
#pragma unroll
        for (int s = 0; s < 8; ++s) v += gatesp[(size_t)s * (BB * 4096) + o];
        g[gi] = v;
    }
    const float si = 1.f / (1.f + expf(-g[0]));
    const float sf = 1.f / (1.f + expf(-g[1]));
    const float so = 1.f / (1.f + expf(-g[3]));
    const float tg = tanhf(g[2]);
    const float c = c_prev[idx];
    const float cnv = sf * c + si * tg;
    const float hnv = so * tanhf(cnv);
    cn[idx] = cnv;
    hn[idx] = hnv;
}

// ==== K6: lh GEMM (512 blocks) ====
__global__ __launch_bounds__(256) void k6_lh(
    const float* __restrict__ hn, const float* __restrict__ Lh_w,
    float* __restrict__ dp_hi)
{
    __shared__ __align__(16) unsigned char smem[36864];
    short (*As)[64][72] = (short (*)[64][72])smem;
    short (*Bs)[64][72] = (short (*)[64][72])(smem + 18432);
    const int bid = blockIdx.x;                       // 512 = 4*8*16
    GSrc s1 = {hn, NN, Lh_w, NN, 16, NN};
    GSrc s2 = {nullptr, 0, nullptr, 0, 0, 0};
    gemm_body(bid & 3, (bid >> 2) & 7, bid >> 5, 4, s1, s2,
              dp_hi, MM, MM, 1, nullptr, As, Bs);
}

// ==== K7: build deep ====
__global__ __launch_bounds__(256) void k7_deep(
    const float* __restrict__ emb, const float* __restrict__ dp,
    const float* __restrict__ Lh_b, const float* __restrict__ Lz_b,
    float* __restrict__ deep)
{
    const int idx = blockIdx.x * 256 + threadIdx.x;   // < B*512
    const int j = idx & 511;
    float v = emb[idx] + Lh_b[j] + Lz_b[j];
#pragma unroll
    for (int s = 0; s < 24; ++s) v += dp[(size_t)s * (BB * 512) + idx];
    deep[idx] = v;
}

// ==== K8: p_yt GEMM (628 blocks) ====
__global__ __launch_bounds__(256) void k8_pyt(
    const float* __restrict__ deep, const float* __restrict__ Lo_w,
    const float* __restrict__ Lo_b, float* __restrict__ out)
{
    __shared__ __align__(16) unsigned char smem[36864];
    short (*As)[64][72] = (short (*)[64][72])smem;
    short (*Bs)[64][72] = (short (*)[64][72])(smem + 18432);
    const int bid = blockIdx.x;                       // 628 = 4*157
    GSrc s1 = {deep, MM, Lo_w, MM, 8, MM};
    GSrc s2 = {nullptr, 0, nullptr, 0, 0, 0};
    gemm_body(bid & 3, bid >> 2, 0, 4, s1, s2,
              out, KK, KK, 8, Lo_b, As, Bs);
}

extern "C" void kernel_launch(void* const* d_in, const int* in_sizes, int n_in,
                              void* d_out, int out_size, void* d_ws, size_t ws_size,
                              hipStream_t stream)
{
    const float* a_i     = (const float*)d_in[0];
    const float* inp     = (const float*)d_in[1];
    const float* hn_prev = (const float*)d_in[2];
    const float* cn_prev = (const float*)d_in[3];
    const float* f_att_w = (const float*)d_in[4];
    const float* f_att_b = (const float*)d_in[5];
    const float* gate_w  = (const float*)d_in[6];
    const float* gate_b  = (const float*)d_in[7];
    const float* E_w     = (const float*)d_in[8];
    const float* E_b     = (const float*)d_in[9];
    const float* W_ih    = (const float*)d_in[10];
    const float* W_hh    = (const float*)d_in[11];
    const float* b_ih    = (const float*)d_in[12];
    const float* b_hh    = (const float*)d_in[13];
    const float* Lh_w    = (const float*)d_in[14];
    const float* Lh_b    = (const float*)d_in[15];
    const float* Lz_w    = (const float*)d_in[16];
    const float* Lz_b    = (const float*)d_in[17];
    const float* Lo_w    = (const float*)d_in[18];
    const float* Lo_b    = (const float*)d_in[19];

    float* out = (float*)d_out;
    float* ws  = (float*)d_ws;

    float* PE     = ws + OFF_PE;
    float* BETA   = ws + OFF_BETA;
    float* Z      = ws + OFF_Z;
    float* EMB    = ws + OFF_EMB;
    float* DEEP   = ws + OFF_DEEP;
    float* EMBP   = ws + OFF_EMBP;
    float* GATESP = ws + OFF_GATESP;
    float* DP     = ws + OFF_DP;

    // K1: att_e partials || emb GEMM || gates_h GEMM
    k1_atte_emb_gatesh<<<5376, 256, 0, stream>>>(
        a_i, f_att_w, PE, inp, E_w, EMBP, hn_prev, W_ih, W_hh, GATESP);

    // K2: softmax+beta || emb reduce
    k2_softmax_embred<<<768, 256, 0, stream>>>(PE, hn_prev, f_att_w, f_att_b,
                                               gate_w, gate_b, out + OUT_AL, BETA,
                                               EMBP, E_b, EMB);

    // K3: att_z (L3-hot a_i) || gates_e GEMM (slices 4..5)
    k3_attz_gatese<<<4608, 256, 0, stream>>>(a_i, out + OUT_AL, BETA, Z,
                                             EMB, W_ih,
                                             GATESP + (size_t)4 * BB * 4096);

    // K4: gates_z GEMM (slices 6..7) || lz GEMM (dp slices 0..7)
    k4_gatesz_lz<<<768, 256, 0, stream>>>(Z, W_ih,
                                          GATESP + (size_t)6 * BB * 4096,
                                          Lz_w, DP);

    // K5: LSTM cell
    k5_lstm<<<1024, 256, 0, stream>>>(GATESP, b_ih, b_hh, cn_prev,
                                      out + OUT_HN, out + OUT_CN);

    // K6: hn@Lh_w^T (dp slices 8..23)
    k6_lh<<<512, 256, 0, stream>>>(out + OUT_HN, Lh_w,
                                   DP + (size_t)8 * BB * 512);

    // K7: deep = emb + sum(dp) + biases
    k7_deep<<<512, 256, 0, stream>>>(EMB, DP, Lh_b, Lz_b, DEEP);

    // K8: p_yt = deep @ Lo_w^T + Lo_b
    k8_pyt<<<628, 256, 0, stream>>>(DEEP, Lo_w, Lo_b, out + OUT_PY);
}